// Round 8
// baseline (423.931 us; speedup 1.0000x reference)
//
#include <hip/hip_runtime.h>

// NeuralHashVoxel round 8:
//  - binsort fused INTO main kernel (per-bin LDS sub-sort -> process in place)
//  - bmbuild + hist fused into one kernel (independent block ranges)
//  - lean main path: recompute per-level hash/fractions, 2-batch bitmap probe,
//    __launch_bounds__(256,7) to raise occupancy (VGPR cap ~73)
//  - binbase moved to d_ws (main kernel reads it while writing d_out)

static constexpr int      NPTS  = 1048576;
static constexpr int      LVLS  = 6;
static constexpr int      NF    = 8;
static constexpr int      TTAB  = 524288;
static constexpr unsigned BTAB  = 4194304u;          // 2^22 buckets per level
static constexpr unsigned BMASK = BTAB - 1u;
static constexpr unsigned P0 = 73856093u, P1 = 19349669u, P2 = 83492791u;

static constexpr int NBIN = 4096;        // 16^3 Morton bins, cell = 3.125
static constexpr int SB   = 256;         // sort blocks
static constexpr int PPB  = NPTS / SB;   // 4096 points per sort block
static constexpr int ITER = PPB / 256;
static constexpr int BCAP = 512;         // per-bin LDS capacity (avg 256)

static constexpr int    BMW_L        = BTAB / 32;                  // bitmap words/level
static constexpr int    BM_BLOCKS    = LVLS * BMW_L / 256;         // 3072
static constexpr size_t SORTED_BYTES = (size_t)NPTS * 16;          // 16 MB
static constexpr size_t BM_BYTES     = (size_t)LVLS * BMW_L * 4;   // 3 MB
static constexpr size_t BB_BYTES     = (size_t)NBIN * 4;           // 16 KB
static constexpr size_t WS_FULL      = SORTED_BYTES + BM_BYTES + BB_BYTES;

typedef float f4 __attribute__((ext_vector_type(4)));
typedef int   i4 __attribute__((ext_vector_type(4)));

// ---------------- lean per-point computation, bitmap-gated ------------------
__device__ __forceinline__ void nhv_point_bm(
    float qx, float qy, float qz,
    const float* __restrict__ feat, const int* __restrict__ fidx,
    const unsigned* __restrict__ bm, float acc[NF])
{
    // bitmap probe in two 3-level batches (bounds in-flight regs ~24)
    unsigned vmask = 0;
#pragma unroll
    for (int half = 0; half < 2; ++half) {
        unsigned hh[3];
#pragma unroll
        for (int j = 0; j < 3; ++j) {
            const int i = half * 3 + j;
            const float inv = 4.0f / (float)(1 << i);
            const float bx = floorf(qx * inv), by = floorf(qy * inv), bz = floorf(qz * inv);
            hh[j] = (unsigned)(int)bx * P0 + (unsigned)(int)by * P1 + (unsigned)(int)bz * P2;
        }
#pragma unroll
        for (int j = 0; j < 3; ++j) {
            const unsigned* __restrict__ bl = bm + (size_t)(half * 3 + j) * BMW_L;
            unsigned vv = ~0u;
#pragma unroll
            for (int k = 0; k < 8; ++k) {
                unsigned key = hh[j];
                if (k & 4) key += P0;
                if (k & 2) key += P1;
                if (k & 1) key += P2;
                key &= BMASK;
                vv &= (bl[key >> 5] >> (key & 31u));
            }
            vmask |= (vv & 1u) << (half * 3 + j);
        }
    }

#pragma unroll
    for (int f = 0; f < NF; ++f) acc[f] = 0.0f;

#pragma unroll
    for (int i = 0; i < LVLS; ++i) {
        if (vmask & (1u << i)) {          // all 8 corners valid -> idx in [0,T)
            const float inv = 4.0f / (float)(1 << i);
            const float sx = qx * inv, sy = qy * inv, sz = qz * inv;
            const float bx = floorf(sx), by = floorf(sy), bz = floorf(sz);
            const unsigned h = (unsigned)(int)bx * P0 + (unsigned)(int)by * P1
                             + (unsigned)(int)bz * P2;
            const int* __restrict__ tab = fidx + (size_t)i * BTAB;
            int id[8];
#pragma unroll
            for (int k = 0; k < 8; ++k) {
                unsigned key = h;
                if (k & 4) key += P0;
                if (k & 2) key += P1;
                if (k & 1) key += P2;
                id[k] = tab[key & BMASK];
            }
            const float tx = sx - bx, ty = sy - by, tz = sz - bz;
            const float wxv[2] = {1.0f - tx, tx};
            const float wyv[2] = {1.0f - ty, ty};
            const float wzv[2] = {1.0f - tz, tz};
            const float* __restrict__ fb = feat + (size_t)i * (TTAB * NF);
#pragma unroll
            for (int k = 0; k < 8; ++k) {
                const float c = wxv[(k >> 2) & 1] * wyv[(k >> 1) & 1] * wzv[k & 1];
                const float4* p = (const float4*)(fb + (size_t)id[k] * NF);
                const float4 lo = p[0];
                const float4 hi = p[1];
                acc[0] += c * lo.x; acc[1] += c * lo.y;
                acc[2] += c * lo.z; acc[3] += c * lo.w;
                acc[4] += c * hi.x; acc[5] += c * hi.y;
                acc[6] += c * hi.z; acc[7] += c * hi.w;
            }
        }
    }
}

// ---------------- plain per-point (ws-too-small fallback) -------------------
__device__ __forceinline__ void nhv_point(
    float qx, float qy, float qz,
    const float* __restrict__ feat, const int* __restrict__ fidx, float acc[NF])
{
    float    fx[LVLS], fy[LVLS], fz[LVLS];
    unsigned h[LVLS];
#pragma unroll
    for (int i = 0; i < LVLS; ++i) {
        const float inv = 4.0f / (float)(1 << i);
        const float sx = qx * inv, sy = qy * inv, sz = qz * inv;
        const float bx = floorf(sx), by = floorf(sy), bz = floorf(sz);
        fx[i] = sx - bx; fy[i] = sy - by; fz[i] = sz - bz;
        h[i] = (unsigned)(int)bx * P0 + (unsigned)(int)by * P1 + (unsigned)(int)bz * P2;
    }
    int id[LVLS][8];
#pragma unroll
    for (int i = 0; i < LVLS; ++i) {
        const int* __restrict__ tab = fidx + (size_t)i * BTAB;
#pragma unroll
        for (int k = 0; k < 8; ++k) {
            unsigned key = h[i];
            if (k & 4) key += P0;
            if (k & 2) key += P1;
            if (k & 1) key += P2;
            id[i][k] = tab[key & BMASK];
        }
    }
#pragma unroll
    for (int f = 0; f < NF; ++f) acc[f] = 0.0f;
#pragma unroll
    for (int i = 0; i < LVLS; ++i) {
        int mn = id[i][0];
#pragma unroll
        for (int k = 1; k < 8; ++k) mn = min(mn, id[i][k]);
        if (mn > -1) {
            const float wxv[2] = {1.0f - fx[i], fx[i]};
            const float wyv[2] = {1.0f - fy[i], fy[i]};
            const float wzv[2] = {1.0f - fz[i], fz[i]};
            const float* __restrict__ fb = feat + (size_t)i * (TTAB * NF);
#pragma unroll
            for (int k = 0; k < 8; ++k) {
                const float c = wxv[(k >> 2) & 1] * wyv[(k >> 1) & 1] * wzv[k & 1];
                const float4* p = (const float4*)(fb + (size_t)id[i][k] * NF);
                const float4 lo = p[0];
                const float4 hi = p[1];
                acc[0] += c * lo.x; acc[1] += c * lo.y;
                acc[2] += c * lo.z; acc[3] += c * lo.w;
                acc[4] += c * hi.x; acc[5] += c * hi.y;
                acc[6] += c * hi.z; acc[7] += c * hi.w;
            }
        }
    }
}

// ---------------- binning ----------------
__device__ __forceinline__ unsigned expand4(unsigned v) {
    return (v & 1u) | ((v & 2u) << 2) | ((v & 4u) << 4) | ((v & 8u) << 6);
}
__device__ __forceinline__ unsigned bin_of(float x, float y, float z) {
    unsigned bx = min(15u, (unsigned)(int)(x * 0.32f));
    unsigned by = min(15u, (unsigned)(int)(y * 0.32f));
    unsigned bz = min(15u, (unsigned)(int)(z * 0.32f));
    return expand4(bx) | (expand4(by) << 1) | (expand4(bz) << 2);
}

// ---------------- fused pre-pass: bitmap build || histogram -----------------
__global__ __launch_bounds__(256) void pre_k(const int* __restrict__ fidx,
                                             unsigned* __restrict__ bm,
                                             const float* __restrict__ qp,
                                             unsigned* __restrict__ hist) {
    __shared__ unsigned lh[NBIN];
    const int t = threadIdx.x;
    if (blockIdx.x < BM_BLOCKS) {
        // bitmap part: 1 bit per bucket = (idx >= 0)
        const int g = blockIdx.x * 256 + t;
        const i4* p = (const i4*)(fidx + (size_t)g * 32);
        unsigned w = 0;
#pragma unroll
        for (int j = 0; j < 8; ++j) {
            const i4 v = __builtin_nontemporal_load(p + j);
            w |= (unsigned)(v.x >= 0) << (4 * j + 0);
            w |= (unsigned)(v.y >= 0) << (4 * j + 1);
            w |= (unsigned)(v.z >= 0) << (4 * j + 2);
            w |= (unsigned)(v.w >= 0) << (4 * j + 3);
        }
        bm[g] = w;
    } else {
        // histogram part
        const int b = blockIdx.x - BM_BLOCKS;
        for (int i = t; i < NBIN; i += 256) lh[i] = 0u;
        __syncthreads();
        const int base = b * PPB;
#pragma unroll
        for (int i = 0; i < ITER; ++i) {
            const int p = base + i * 256 + t;
            atomicAdd(&lh[bin_of(qp[3*p], qp[3*p+1], qp[3*p+2])], 1u);
        }
        __syncthreads();
        for (int i = t; i < NBIN; i += 256) hist[(size_t)b * NBIN + i] = lh[i];
    }
}

__global__ __launch_bounds__(256) void colscan_k(unsigned* __restrict__ hist,
                                                 unsigned* __restrict__ binbase) {
    const int bin = blockIdx.x * 256 + threadIdx.x;   // 16 blocks
    unsigned run = 0;
    for (int b = 0; b < SB; ++b) {
        const unsigned v = hist[(size_t)b * NBIN + bin];
        hist[(size_t)b * NBIN + bin] = run;
        run += v;
    }
    binbase[bin] = run;
}

__global__ __launch_bounds__(256) void binscan_k(unsigned* __restrict__ binbase) {
    __shared__ unsigned tot[256];
    const int t = threadIdx.x;
    unsigned v[16];
    unsigned s = 0;
#pragma unroll
    for (int i = 0; i < 16; ++i) { v[i] = s; s += binbase[t * 16 + i]; }
    tot[t] = s;
    __syncthreads();
    for (int d = 1; d < 256; d <<= 1) {
        const unsigned x = (t >= d) ? tot[t - d] : 0u;
        __syncthreads();
        tot[t] += x;
        __syncthreads();
    }
    const unsigned cb = tot[t] - s;
#pragma unroll
    for (int i = 0; i < 16; ++i) binbase[t * 16 + i] = cb + v[i];
}

__global__ __launch_bounds__(256) void scatter_k(const float* __restrict__ qp,
                                                 const unsigned* __restrict__ hist,
                                                 const unsigned* __restrict__ binbase,
                                                 float4* __restrict__ sorted) {
    __shared__ unsigned cur[NBIN];
    const int b = blockIdx.x, t = threadIdx.x;
    for (int i = t; i < NBIN; i += 256)
        cur[i] = binbase[i] + hist[(size_t)b * NBIN + i];
    __syncthreads();
    const int base = b * PPB;
#pragma unroll
    for (int i = 0; i < ITER; ++i) {
        const int p = base + i * 256 + t;
        const float x = qp[3*p], y = qp[3*p+1], z = qp[3*p+2];
        const unsigned slot = atomicAdd(&cur[bin_of(x, y, z)], 1u);
        sorted[slot] = make_float4(x, y, z, __uint_as_float((unsigned)p));
    }
}

// -------- main kernel: per-bin LDS sub-sort (6-bit sub-Morton) + gather -----
__global__ __launch_bounds__(256, 7) void nhv_main_k(
    const float4* __restrict__ sorted, const unsigned* __restrict__ binbase,
    const float* __restrict__ feat, const int* __restrict__ fidx,
    const unsigned* __restrict__ bm, float* __restrict__ out)
{
    __shared__ float4         pts[BCAP];   // 8 KB
    __shared__ unsigned char  sk[BCAP];
    __shared__ unsigned short ord[BCAP];
    __shared__ unsigned       cnt[64];

    const int bid = blockIdx.x;
    const int bin = (bid & 7) * (NBIN >> 3) + (bid >> 3);   // XCD spatial slabs
    const int t   = threadIdx.x;
    const unsigned start = binbase[bin];
    const unsigned end   = (bin < NBIN - 1) ? binbase[bin + 1] : (unsigned)NPTS;
    const int n = (int)(end - start);

    if (n <= BCAP) {
        if (t < 64) cnt[t] = 0u;
        __syncthreads();
#pragma unroll
        for (int r = 0; r < BCAP / 256; ++r) {
            const int i = r * 256 + t;
            if (i < n) {
                const f4 pv = __builtin_nontemporal_load((const f4*)sorted + (start + i));
                const float4 p = make_float4(pv.x, pv.y, pv.z, pv.w);
                pts[i] = p;
                // 0.78125-cell local sub-Morton (2 bits/axis, coarse bit high)
                const unsigned ux = (unsigned)(int)(p.x * 1.28f) & 3u;
                const unsigned uy = (unsigned)(int)(p.y * 1.28f) & 3u;
                const unsigned uz = (unsigned)(int)(p.z * 1.28f) & 3u;
                const unsigned s = (ux & 1u) | ((uy & 1u) << 1) | ((uz & 1u) << 2)
                                 | ((ux >> 1) << 3) | ((uy >> 1) << 4) | ((uz >> 1) << 5);
                sk[i] = (unsigned char)s;
                atomicAdd(&cnt[s], 1u);
            }
        }
        __syncthreads();
        if (t == 0) {
            unsigned run = 0;
#pragma unroll
            for (int i = 0; i < 64; ++i) { const unsigned v = cnt[i]; cnt[i] = run; run += v; }
        }
        __syncthreads();
#pragma unroll
        for (int r = 0; r < BCAP / 256; ++r) {
            const int i = r * 256 + t;
            if (i < n) ord[atomicAdd(&cnt[sk[i]], 1u)] = (unsigned short)i;
        }
        __syncthreads();
#pragma unroll
        for (int r = 0; r < BCAP / 256; ++r) {
            const int j = r * 256 + t;
            if (j < n) {
                const float4 p = pts[ord[j]];
                float acc[NF];
                nhv_point_bm(p.x, p.y, p.z, feat, fidx, bm, acc);
                const unsigned pn = __float_as_uint(p.w);
                f4* o = (f4*)(out + (size_t)pn * NF);
                f4 lo = {acc[0], acc[1], acc[2], acc[3]};
                f4 hi = {acc[4], acc[5], acc[6], acc[7]};
                __builtin_nontemporal_store(lo, o);
                __builtin_nontemporal_store(hi, o + 1);
            }
        }
    } else {  // oversize bin (rare): process unsorted, still correct
        for (int j = t; j < n; j += 256) {
            const f4 pv = __builtin_nontemporal_load((const f4*)sorted + (start + j));
            float acc[NF];
            nhv_point_bm(pv.x, pv.y, pv.z, feat, fidx, bm, acc);
            const unsigned pn = __float_as_uint(pv.w);
            f4* o = (f4*)(out + (size_t)pn * NF);
            f4 lo = {acc[0], acc[1], acc[2], acc[3]};
            f4 hi = {acc[4], acc[5], acc[6], acc[7]};
            __builtin_nontemporal_store(lo, o);
            __builtin_nontemporal_store(hi, o + 1);
        }
    }
}

// ---------------- fallback ----------------
__global__ __launch_bounds__(256) void nhv_direct_k(
    const float* __restrict__ qp, const float* __restrict__ feat,
    const int* __restrict__ fidx, float* __restrict__ out)
{
    const int n = blockIdx.x * 256 + threadIdx.x;
    if (n >= NPTS) return;
    float acc[NF];
    nhv_point(qp[3*n], qp[3*n+1], qp[3*n+2], feat, fidx, acc);
    float4* o = (float4*)(out + (size_t)n * NF);
    o[0] = make_float4(acc[0], acc[1], acc[2], acc[3]);
    o[1] = make_float4(acc[4], acc[5], acc[6], acc[7]);
}

extern "C" void kernel_launch(void* const* d_in, const int* in_sizes, int n_in,
                              void* d_out, int out_size, void* d_ws, size_t ws_size,
                              hipStream_t stream) {
    const float* qp   = (const float*)d_in[0];
    const float* feat = (const float*)d_in[1];
    const int*   fidx = (const int*)d_in[2];
    float*       out  = (float*)d_out;

    if (ws_size >= WS_FULL) {
        // ws: sorted (16 MB) | bm (3 MB) | binbase (16 KB)
        float4*   sorted  = (float4*)d_ws;
        unsigned* bm      = (unsigned*)((char*)d_ws + SORTED_BYTES);
        unsigned* binbase = (unsigned*)((char*)d_ws + SORTED_BYTES + BM_BYTES);
        // hist (4 MB) lives in d_out: only read by colscan/scatter, which
        // complete before nhv_main_k overwrites d_out. Deterministic.
        unsigned* hist    = (unsigned*)d_out;

        hipLaunchKernelGGL(pre_k,     dim3(BM_BLOCKS + SB), dim3(256), 0, stream,
                           fidx, bm, qp, hist);
        hipLaunchKernelGGL(colscan_k, dim3(16),  dim3(256), 0, stream, hist, binbase);
        hipLaunchKernelGGL(binscan_k, dim3(1),   dim3(256), 0, stream, binbase);
        hipLaunchKernelGGL(scatter_k, dim3(SB),  dim3(256), 0, stream, qp, hist, binbase, sorted);
        hipLaunchKernelGGL(nhv_main_k, dim3(NBIN), dim3(256), 0, stream,
                           sorted, binbase, feat, fidx, bm, out);
    } else {
        hipLaunchKernelGGL(nhv_direct_k, dim3(NPTS/256), dim3(256), 0, stream,
                           qp, feat, fidx, out);
    }
}

// Round 9
// 197.941 us; speedup vs baseline: 2.1417x; 2.1417x over previous
//
#include <hip/hip_runtime.h>

// NeuralHashVoxel round 9:
//  - main kernel reverted to the proven r6 structure (no occupancy cap, no
//    bucket-bitmap -> no spills, no 96 MB bitmap build)
//  - NEW: per-level spatial cell-validity bit-grids for levels 2..5 (tiny
//    vertex sets): occ[vertex]=(fidx[hash]>=0) built via wave-ballot (153K
//    probes), cbit[cell]=AND of 8 corners. Main tests 1 L1-resident u64 per
//    coarse level instead of 8 divergent random idx probes -> big cut in
//    L1/TA transactions (the measured bottleneck; r6->r7 showed bytes aren't).
//  - levels 0..1 keep direct min-gated probes (grid is zero-sum there).

static constexpr int      NPTS  = 1048576;
static constexpr int      NF    = 8;
static constexpr int      TTAB  = 524288;
static constexpr unsigned BTAB  = 4194304u;          // 2^22 buckets per level
static constexpr unsigned BMASK = BTAB - 1u;
static constexpr unsigned P0 = 73856093u, P1 = 19349669u, P2 = 83492791u;

static constexpr int NBIN = 4096;        // 16^3 Morton bins, cell = 3.125
static constexpr int SB   = 256;         // sort blocks
static constexpr int PPB  = NPTS / SB;
static constexpr int ITER = PPB / 256;
static constexpr int BCAP = 512;

// vertex-grid dims for levels 2..5 (scaled coords < 50,25,12.5,6.25)
static constexpr int S2 = 51, S3 = 26, S4 = 14, S5 = 8;          // vertices/axis
static constexpr int OCC2 = 0, OCC3 = OCC2 + S2*S2, OCC4 = OCC3 + S3*S3,
                     OCC5 = OCC4 + S4*S4, OCCW = OCC5 + S5*S5;   // u64 rows
static constexpr int CB2 = 0, CB3 = CB2 + (S2-1)*(S2-1),
                     CB4 = CB3 + (S3-1)*(S3-1), CB5 = CB4 + (S4-1)*(S4-1),
                     CBW = CB5 + (S5-1)*(S5-1);                  // u64 rows

// pre_k occ-build block partition (1 wave per 64-vertex row, 4 rows/block)
static constexpr int RB2 = (S2*S2+3)/4, RB3 = (S3*S3+3)/4,
                     RB4 = (S4*S4+3)/4, RB5 = (S5*S5+3)/4;
static constexpr int OCCB = RB2+RB3+RB4+RB5;                     // 885 blocks

static constexpr size_t SORTED_BYTES = (size_t)NPTS * 16;        // 16 MB
static constexpr size_t OCC_OFF = SORTED_BYTES;
static constexpr size_t CB_OFF  = OCC_OFF + (size_t)OCCW * 8;
static constexpr size_t BB_OFF  = CB_OFF  + (size_t)CBW  * 8;
static constexpr size_t WS_FULL = BB_OFF + (size_t)NBIN * 4;     // ~16.07 MB

typedef float f4 __attribute__((ext_vector_type(4)));

// ---------------- main per-point computation (grid-gated coarse levels) -----
__device__ __forceinline__ void nhv_point_g(
    float qx, float qy, float qz,
    const float* __restrict__ feat, const int* __restrict__ fidx,
    const unsigned long long* __restrict__ cbit, float acc[NF])
{
    // levels 0,1: direct probes, all 16 issued back-to-back
    float fx01[2], fy01[2], fz01[2];
    unsigned h01[2];
#pragma unroll
    for (int i = 0; i < 2; ++i) {
        const float inv = (i == 0) ? 4.0f : 2.0f;      // exact pow2
        const float sx = qx*inv, sy = qy*inv, sz = qz*inv;
        const float bx = floorf(sx), by = floorf(sy), bz = floorf(sz);
        fx01[i] = sx-bx; fy01[i] = sy-by; fz01[i] = sz-bz;
        h01[i] = (unsigned)(int)bx*P0 + (unsigned)(int)by*P1 + (unsigned)(int)bz*P2;
    }
    int id0[8], id1[8];
#pragma unroll
    for (int k = 0; k < 8; ++k) {
        unsigned key = h01[0];
        if (k & 4) key += P0;
        if (k & 2) key += P1;
        if (k & 1) key += P2;
        id0[k] = fidx[key & BMASK];
    }
#pragma unroll
    for (int k = 0; k < 8; ++k) {
        unsigned key = h01[1];
        if (k & 4) key += P0;
        if (k & 2) key += P1;
        if (k & 1) key += P2;
        id1[k] = fidx[BTAB + (key & BMASK)];
    }

    // levels 2..5: one cbit u64 row per level (L1-resident)
    float fxh[4], fyh[4], fzh[4];
    int   ixh[4], iyh[4], izh[4];
    unsigned vhi = 0;
    const int Ss[4]  = {S2, S3, S4, S5};
    const int CBo[4] = {CB2, CB3, CB4, CB5};
#pragma unroll
    for (int j = 0; j < 4; ++j) {
        const float inv = 1.0f / (float)(1 << j);      // 1, .5, .25, .125
        const float sx = qx*inv, sy = qy*inv, sz = qz*inv;
        const float bx = floorf(sx), by = floorf(sy), bz = floorf(sz);
        fxh[j] = sx-bx; fyh[j] = sy-by; fzh[j] = sz-bz;
        ixh[j] = (int)bx; iyh[j] = (int)by; izh[j] = (int)bz;
        const int C = Ss[j] - 1;
        const unsigned long long row = cbit[CBo[j] + izh[j]*C + iyh[j]];
        vhi |= (unsigned)((row >> ixh[j]) & 1ull) << j;
    }

#pragma unroll
    for (int f = 0; f < NF; ++f) acc[f] = 0.0f;

    // level 0
    {
        int mn = id0[0];
#pragma unroll
        for (int k = 1; k < 8; ++k) mn = min(mn, id0[k]);
        if (mn > -1) {
            const float wxv[2] = {1.0f - fx01[0], fx01[0]};
            const float wyv[2] = {1.0f - fy01[0], fy01[0]};
            const float wzv[2] = {1.0f - fz01[0], fz01[0]};
#pragma unroll
            for (int k = 0; k < 8; ++k) {
                const float c = wxv[(k>>2)&1] * wyv[(k>>1)&1] * wzv[k&1];
                const float4* p = (const float4*)(feat + (size_t)id0[k] * NF);
                const float4 lo = p[0], hi = p[1];
                acc[0]+=c*lo.x; acc[1]+=c*lo.y; acc[2]+=c*lo.z; acc[3]+=c*lo.w;
                acc[4]+=c*hi.x; acc[5]+=c*hi.y; acc[6]+=c*hi.z; acc[7]+=c*hi.w;
            }
        }
    }
    // level 1
    {
        int mn = id1[0];
#pragma unroll
        for (int k = 1; k < 8; ++k) mn = min(mn, id1[k]);
        if (mn > -1) {
            const float wxv[2] = {1.0f - fx01[1], fx01[1]};
            const float wyv[2] = {1.0f - fy01[1], fy01[1]};
            const float wzv[2] = {1.0f - fz01[1], fz01[1]};
            const float* __restrict__ fb = feat + (size_t)(TTAB * NF);
#pragma unroll
            for (int k = 0; k < 8; ++k) {
                const float c = wxv[(k>>2)&1] * wyv[(k>>1)&1] * wzv[k&1];
                const float4* p = (const float4*)(fb + (size_t)id1[k] * NF);
                const float4 lo = p[0], hi = p[1];
                acc[0]+=c*lo.x; acc[1]+=c*lo.y; acc[2]+=c*lo.z; acc[3]+=c*lo.w;
                acc[4]+=c*hi.x; acc[5]+=c*hi.y; acc[6]+=c*hi.z; acc[7]+=c*hi.w;
            }
        }
    }
    // levels 2..5 (grid says valid -> all 8 idx >= 0, gather directly)
#pragma unroll
    for (int j = 0; j < 4; ++j) {
        if (vhi & (1u << j)) {
            const int lvl = 2 + j;
            const unsigned h = (unsigned)ixh[j]*P0 + (unsigned)iyh[j]*P1
                             + (unsigned)izh[j]*P2;
            const int* __restrict__ tab = fidx + (size_t)lvl * BTAB;
            int id[8];
#pragma unroll
            for (int k = 0; k < 8; ++k) {
                unsigned key = h;
                if (k & 4) key += P0;
                if (k & 2) key += P1;
                if (k & 1) key += P2;
                id[k] = tab[key & BMASK];
            }
            const float wxv[2] = {1.0f - fxh[j], fxh[j]};
            const float wyv[2] = {1.0f - fyh[j], fyh[j]};
            const float wzv[2] = {1.0f - fzh[j], fzh[j]};
            const float* __restrict__ fb = feat + (size_t)lvl * (TTAB * NF);
#pragma unroll
            for (int k = 0; k < 8; ++k) {
                const float c = wxv[(k>>2)&1] * wyv[(k>>1)&1] * wzv[k&1];
                const float4* p = (const float4*)(fb + (size_t)id[k] * NF);
                const float4 lo = p[0], hi = p[1];
                acc[0]+=c*lo.x; acc[1]+=c*lo.y; acc[2]+=c*lo.z; acc[3]+=c*lo.w;
                acc[4]+=c*hi.x; acc[5]+=c*hi.y; acc[6]+=c*hi.z; acc[7]+=c*hi.w;
            }
        }
    }
}

// ---------------- plain per-point (ws-too-small fallback) -------------------
__device__ __forceinline__ void nhv_point(
    float qx, float qy, float qz,
    const float* __restrict__ feat, const int* __restrict__ fidx, float acc[NF])
{
    float fx[6], fy[6], fz[6];
    unsigned h[6];
#pragma unroll
    for (int i = 0; i < 6; ++i) {
        const float inv = 4.0f / (float)(1 << i);
        const float sx = qx*inv, sy = qy*inv, sz = qz*inv;
        const float bx = floorf(sx), by = floorf(sy), bz = floorf(sz);
        fx[i] = sx-bx; fy[i] = sy-by; fz[i] = sz-bz;
        h[i] = (unsigned)(int)bx*P0 + (unsigned)(int)by*P1 + (unsigned)(int)bz*P2;
    }
    int id[6][8];
#pragma unroll
    for (int i = 0; i < 6; ++i) {
        const int* __restrict__ tab = fidx + (size_t)i * BTAB;
#pragma unroll
        for (int k = 0; k < 8; ++k) {
            unsigned key = h[i];
            if (k & 4) key += P0;
            if (k & 2) key += P1;
            if (k & 1) key += P2;
            id[i][k] = tab[key & BMASK];
        }
    }
#pragma unroll
    for (int f = 0; f < NF; ++f) acc[f] = 0.0f;
#pragma unroll
    for (int i = 0; i < 6; ++i) {
        int mn = id[i][0];
#pragma unroll
        for (int k = 1; k < 8; ++k) mn = min(mn, id[i][k]);
        if (mn > -1) {
            const float wxv[2] = {1.0f - fx[i], fx[i]};
            const float wyv[2] = {1.0f - fy[i], fy[i]};
            const float wzv[2] = {1.0f - fz[i], fz[i]};
            const float* __restrict__ fb = feat + (size_t)i * (TTAB * NF);
#pragma unroll
            for (int k = 0; k < 8; ++k) {
                const float c = wxv[(k>>2)&1] * wyv[(k>>1)&1] * wzv[k&1];
                const float4* p = (const float4*)(fb + (size_t)id[i][k] * NF);
                const float4 lo = p[0], hi = p[1];
                acc[0]+=c*lo.x; acc[1]+=c*lo.y; acc[2]+=c*lo.z; acc[3]+=c*lo.w;
                acc[4]+=c*hi.x; acc[5]+=c*hi.y; acc[6]+=c*hi.z; acc[7]+=c*hi.w;
            }
        }
    }
}

// ---------------- binning ----------------
__device__ __forceinline__ unsigned expand4(unsigned v) {
    return (v & 1u) | ((v & 2u) << 2) | ((v & 4u) << 4) | ((v & 8u) << 6);
}
__device__ __forceinline__ unsigned bin_of(float x, float y, float z) {
    unsigned bx = min(15u, (unsigned)(int)(x * 0.32f));
    unsigned by = min(15u, (unsigned)(int)(y * 0.32f));
    unsigned bz = min(15u, (unsigned)(int)(z * 0.32f));
    return expand4(bx) | (expand4(by) << 1) | (expand4(bz) << 2);
}

// --------- pre_k: occ-grid build (levels 2..5, wave-ballot) || histogram ----
__global__ __launch_bounds__(256) void pre_k(const int* __restrict__ fidx,
                                             unsigned long long* __restrict__ occ,
                                             const float* __restrict__ qp,
                                             unsigned* __restrict__ hist) {
    __shared__ unsigned lh[NBIN];
    const int t = threadIdx.x, b = blockIdx.x;
    if (b < OCCB) {
        int lvl, S, occoff, bb = b;
        if (bb < RB2)              { lvl = 2; S = S2; occoff = OCC2; }
        else if ((bb -= RB2) < RB3){ lvl = 3; S = S3; occoff = OCC3; }
        else if ((bb -= RB3) < RB4){ lvl = 4; S = S4; occoff = OCC4; }
        else        { bb -= RB4;     lvl = 5; S = S5; occoff = OCC5; }
        const int row  = bb * 4 + (t >> 6);
        const int lane = t & 63;
        if (row < S * S) {
            const int y = row % S, z = row / S;
            bool v = false;
            if (lane < S) {
                const unsigned key = ((unsigned)lane*P0 + (unsigned)y*P1
                                    + (unsigned)z*P2) & BMASK;
                v = fidx[(size_t)lvl * BTAB + key] >= 0;
            }
            const unsigned long long m = __ballot(v);
            if (lane == 0) occ[occoff + row] = m;
        }
    } else {
        const int bh = b - OCCB;
        for (int i = t; i < NBIN; i += 256) lh[i] = 0u;
        __syncthreads();
        const int base = bh * PPB;
#pragma unroll
        for (int i = 0; i < ITER; ++i) {
            const int p = base + i * 256 + t;
            atomicAdd(&lh[bin_of(qp[3*p], qp[3*p+1], qp[3*p+2])], 1u);
        }
        __syncthreads();
        for (int i = t; i < NBIN; i += 256) hist[(size_t)bh * NBIN + i] = lh[i];
    }
}

// ---------- mid_k: colscan (blocks 0..15) || cbit derivation (16..) ---------
__global__ __launch_bounds__(256) void mid_k(unsigned* __restrict__ hist,
                                             unsigned* __restrict__ binbase,
                                             const unsigned long long* __restrict__ occ,
                                             unsigned long long* __restrict__ cbit) {
    const int t = threadIdx.x, b = blockIdx.x;
    if (b < 16) {
        const int bin = b * 256 + t;
        unsigned run = 0;
        for (int blk = 0; blk < SB; ++blk) {
            const unsigned v = hist[(size_t)blk * NBIN + bin];
            hist[(size_t)blk * NBIN + bin] = run;
            run += v;
        }
        binbase[bin] = run;
    } else {
        const int cr = (b - 16) * 256 + t;
        if (cr >= CBW) return;
        int S, occoff, cboff, local;
        if (cr < CB3)      { S = S2; occoff = OCC2; cboff = CB2; local = cr; }
        else if (cr < CB4) { S = S3; occoff = OCC3; cboff = CB3; local = cr - CB3; }
        else if (cr < CB5) { S = S4; occoff = OCC4; cboff = CB4; local = cr - CB4; }
        else               { S = S5; occoff = OCC5; cboff = CB5; local = cr - CB5; }
        const int C = S - 1;
        const int cy = local % C, cz = local / C;
        const unsigned long long r00 = occ[occoff +  cz      * S + cy    ];
        const unsigned long long r10 = occ[occoff +  cz      * S + cy + 1];
        const unsigned long long r01 = occ[occoff + (cz + 1) * S + cy    ];
        const unsigned long long r11 = occ[occoff + (cz + 1) * S + cy + 1];
        const unsigned long long cw = (r00 & (r00 >> 1)) & (r10 & (r10 >> 1))
                                    & (r01 & (r01 >> 1)) & (r11 & (r11 >> 1));
        cbit[cboff + cz * C + cy] = cw;
    }
}

__global__ __launch_bounds__(256) void binscan_k(unsigned* __restrict__ binbase) {
    __shared__ unsigned tot[256];
    const int t = threadIdx.x;
    unsigned v[16];
    unsigned s = 0;
#pragma unroll
    for (int i = 0; i < 16; ++i) { v[i] = s; s += binbase[t * 16 + i]; }
    tot[t] = s;
    __syncthreads();
    for (int d = 1; d < 256; d <<= 1) {
        const unsigned x = (t >= d) ? tot[t - d] : 0u;
        __syncthreads();
        tot[t] += x;
        __syncthreads();
    }
    const unsigned cb = tot[t] - s;
#pragma unroll
    for (int i = 0; i < 16; ++i) binbase[t * 16 + i] = cb + v[i];
}

__global__ __launch_bounds__(256) void scatter_k(const float* __restrict__ qp,
                                                 const unsigned* __restrict__ hist,
                                                 const unsigned* __restrict__ binbase,
                                                 float4* __restrict__ sorted) {
    __shared__ unsigned cur[NBIN];
    const int b = blockIdx.x, t = threadIdx.x;
    for (int i = t; i < NBIN; i += 256)
        cur[i] = binbase[i] + hist[(size_t)b * NBIN + i];
    __syncthreads();
    const int base = b * PPB;
#pragma unroll
    for (int i = 0; i < ITER; ++i) {
        const int p = base + i * 256 + t;
        const float x = qp[3*p], y = qp[3*p+1], z = qp[3*p+2];
        const unsigned slot = atomicAdd(&cur[bin_of(x, y, z)], 1u);
        sorted[slot] = make_float4(x, y, z, __uint_as_float((unsigned)p));
    }
}

// ------- stage 2: per-bin 64-bucket counting sort (6-bit sub-Morton) --------
__global__ __launch_bounds__(256) void binsort_k(float4* __restrict__ sorted,
                                                 const unsigned* __restrict__ binbase) {
    __shared__ float4        pts[BCAP];
    __shared__ unsigned char sk[BCAP];
    __shared__ unsigned      cnt[64];
    const int bin = blockIdx.x, t = threadIdx.x;
    const unsigned start = binbase[bin];
    const unsigned end   = (bin < NBIN - 1) ? binbase[bin + 1] : (unsigned)NPTS;
    const int n = (int)(end - start);
    if (n <= 1 || n > BCAP) return;

    if (t < 64) cnt[t] = 0u;
    __syncthreads();
#pragma unroll
    for (int r = 0; r < BCAP / 256; ++r) {
        const int i = r * 256 + t;
        if (i < n) {
            const float4 p = sorted[start + i];
            pts[i] = p;
            const unsigned ux = (unsigned)(int)(p.x * 1.28f) & 3u;
            const unsigned uy = (unsigned)(int)(p.y * 1.28f) & 3u;
            const unsigned uz = (unsigned)(int)(p.z * 1.28f) & 3u;
            const unsigned s = (ux & 1u) | ((uy & 1u) << 1) | ((uz & 1u) << 2)
                             | ((ux >> 1) << 3) | ((uy >> 1) << 4) | ((uz >> 1) << 5);
            sk[i] = (unsigned char)s;
            atomicAdd(&cnt[s], 1u);
        }
    }
    __syncthreads();
    if (t == 0) {
        unsigned run = 0;
#pragma unroll
        for (int i = 0; i < 64; ++i) { const unsigned v = cnt[i]; cnt[i] = run; run += v; }
    }
    __syncthreads();
#pragma unroll
    for (int r = 0; r < BCAP / 256; ++r) {
        const int i = r * 256 + t;
        if (i < n) {
            const unsigned dest = atomicAdd(&cnt[sk[i]], 1u);
            sorted[start + dest] = pts[i];
        }
    }
}

// ---------------- main kernel (flat, XCD-slab swizzle) ----------------------
__global__ __launch_bounds__(256) void nhv_main_k(
    const float4* __restrict__ sp, const float* __restrict__ feat,
    const int* __restrict__ fidx, const unsigned long long* __restrict__ cbit,
    float* __restrict__ out)
{
    const int nwg = NPTS / 256;
    const int bid = blockIdx.x;
    const int swz = (bid & 7) * (nwg >> 3) + (bid >> 3);
    const int j   = swz * 256 + (int)threadIdx.x;

    const f4 s = __builtin_nontemporal_load((const f4*)sp + j);
    float acc[NF];
    nhv_point_g(s.x, s.y, s.z, feat, fidx, cbit, acc);
    const unsigned n = __float_as_uint(s.w);
    f4* o = (f4*)(out + (size_t)n * NF);
    f4 lo = {acc[0], acc[1], acc[2], acc[3]};
    f4 hi = {acc[4], acc[5], acc[6], acc[7]};
    __builtin_nontemporal_store(lo, o);
    __builtin_nontemporal_store(hi, o + 1);
}

// ---------------- fallback ----------------
__global__ __launch_bounds__(256) void nhv_direct_k(
    const float* __restrict__ qp, const float* __restrict__ feat,
    const int* __restrict__ fidx, float* __restrict__ out)
{
    const int n = blockIdx.x * 256 + threadIdx.x;
    if (n >= NPTS) return;
    float acc[NF];
    nhv_point(qp[3*n], qp[3*n+1], qp[3*n+2], feat, fidx, acc);
    float4* o = (float4*)(out + (size_t)n * NF);
    o[0] = make_float4(acc[0], acc[1], acc[2], acc[3]);
    o[1] = make_float4(acc[4], acc[5], acc[6], acc[7]);
}

extern "C" void kernel_launch(void* const* d_in, const int* in_sizes, int n_in,
                              void* d_out, int out_size, void* d_ws, size_t ws_size,
                              hipStream_t stream) {
    const float* qp   = (const float*)d_in[0];
    const float* feat = (const float*)d_in[1];
    const int*   fidx = (const int*)d_in[2];
    float*       out  = (float*)d_out;

    if (ws_size >= WS_FULL) {
        float4*             sorted  = (float4*)d_ws;
        unsigned long long* occ     = (unsigned long long*)((char*)d_ws + OCC_OFF);
        unsigned long long* cbit    = (unsigned long long*)((char*)d_ws + CB_OFF);
        unsigned*           binbase = (unsigned*)((char*)d_ws + BB_OFF);
        // hist (4 MB) lives in d_out: consumed by mid_k/scatter_k before
        // nhv_main_k overwrites d_out (same stream, ordered). Deterministic.
        unsigned*           hist    = (unsigned*)d_out;

        // NOTE: occ shares bytes with sorted[0..OCCW*8) ? No — occ is at
        // OCC_OFF = 16 MB, beyond sorted. Total ws need ~16.07 MB.
        hipLaunchKernelGGL(pre_k,    dim3(OCCB + SB), dim3(256), 0, stream,
                           fidx, occ, qp, hist);
        hipLaunchKernelGGL(mid_k,    dim3(16 + (CBW + 255) / 256), dim3(256), 0, stream,
                           hist, binbase, occ, cbit);
        hipLaunchKernelGGL(binscan_k, dim3(1),    dim3(256), 0, stream, binbase);
        hipLaunchKernelGGL(scatter_k, dim3(SB),   dim3(256), 0, stream,
                           qp, hist, binbase, sorted);
        hipLaunchKernelGGL(binsort_k, dim3(NBIN), dim3(256), 0, stream, sorted, binbase);
        hipLaunchKernelGGL(nhv_main_k, dim3(NPTS/256), dim3(256), 0, stream,
                           sorted, feat, fidx, cbit, out);
    } else {
        hipLaunchKernelGGL(nhv_direct_k, dim3(NPTS/256), dim3(256), 0, stream,
                           qp, feat, fidx, out);
    }
}